// Round 2
// baseline (1987.946 us; speedup 1.0000x reference)
//
#include <hip/hip_runtime.h>
#include <stdint.h>

typedef unsigned short u16;
typedef __attribute__((ext_vector_type(8))) short bf16x8;
typedef __attribute__((ext_vector_type(4))) float f32x4;

#define NTOK 49
#define NHEAD 8
#define HDIM 32
#define CH 256
#define NWIN 4096
#define MTOT (NWIN * NTOK)        /* 200704 */
#define QKV_N 768
#define ATT_SCALE 0.17677669529663687f

/* workspace byte offsets */
#define OFF_WQT_X   0u
#define OFF_WQT_R   393216u
#define OFF_WPT_X   786432u
#define OFF_WPT_R   917504u
#define OFF_BIASM   1048576u
#define OFF_QKV_X   2097152u
#define OFF_QKV_R   310378496u    /* 2097152 + 200704*768*2 */

__device__ __forceinline__ float bf2f(u16 u) {
  unsigned int x = ((unsigned int)u) << 16;
  return __builtin_bit_cast(float, x);
}
__device__ __forceinline__ u16 f2bf(float f) {
  unsigned int x = __builtin_bit_cast(unsigned int, f);
  x = x + 0x7FFFu + ((x >> 16) & 1u);
  return (u16)(x >> 16);
}
__device__ __forceinline__ bf16x8 zero8() { bf16x8 z = {0,0,0,0,0,0,0,0}; return z; }
__device__ __forceinline__ f32x4 zero4() { f32x4 z = {0.f,0.f,0.f,0.f}; return z; }

__device__ __forceinline__ void lds_load16(const u16* g, u16* s) {
  __builtin_amdgcn_global_load_lds(
      (const __attribute__((address_space(1))) void*)g,
      (__attribute__((address_space(3))) void*)s, 16, 0, 0);
}

/* stage a 128x32 fp32 tile (row stride 256 f32) into LDS as bf16 [128][32] */
__device__ __forceinline__ void stage_f32_tile(const float* gbase, u16* lds, int tid) {
#pragma unroll
  for (int it = 0; it < 2; ++it) {
    int f = (it * 256 + tid) * 8;
    int row = f >> 5, col = f & 31;
    const float* p = gbase + (size_t)row * 256 + col;
    float4 a = *(const float4*)p;
    float4 b = *(const float4*)(p + 4);
    u16 tmp[8] = {f2bf(a.x), f2bf(a.y), f2bf(a.z), f2bf(a.w),
                  f2bf(b.x), f2bf(b.y), f2bf(b.z), f2bf(b.w)};
    *(bf16x8*)&lds[f] = *(const bf16x8*)tmp;
  }
}

/* ---------------- prep: weight transposes (fp32 -> bf16) + bias matrix ---- */
__global__ __launch_bounds__(256) void prep_kernel(
    const float* __restrict__ w_qkv, const float* __restrict__ w_qkv_r,
    const float* __restrict__ w_proj, const float* __restrict__ w_proj_r,
    const float* __restrict__ bias_table, const int* __restrict__ rel_idx,
    u16* __restrict__ wqT_x, u16* __restrict__ wqT_r,
    u16* __restrict__ wpT_x, u16* __restrict__ wpT_r, float* __restrict__ biasm) {
  int id = blockIdx.x * 256 + threadIdx.x;
  if (id < 196608) {                       /* wqkvT_x: [768][256] bf16 */
    int n = id >> 8, k = id & 255;
    wqT_x[id] = f2bf(w_qkv[k * 768 + n]);
  } else if (id < 393216) {
    int t = id - 196608; int n = t >> 8, k = t & 255;
    wqT_r[t] = f2bf(w_qkv_r[k * 768 + n]);
  } else if (id < 458752) {                /* wprojT_x: [256][256] bf16 */
    int t = id - 393216; int n = t >> 8, k = t & 255;
    wpT_x[t] = f2bf(w_proj[k * 256 + n]);
  } else if (id < 524288) {
    int t = id - 458752; int n = t >> 8, k = t & 255;
    wpT_r[t] = f2bf(w_proj_r[k * 256 + n]);
  } else if (id < 524288 + 19208) {        /* biasm[h][49][49] fp32 */
    int t = id - 524288;
    int h = t / 2401, nm = t % 2401;
    biasm[t] = bias_table[rel_idx[nm] * 8 + h];
  }
}

/* ---------------- qkv GEMM: OUT[m][n] = A[m][:]·WT[n][:] + bias[n] -------- */
/* A fp32 [M][256], WT bf16 [768][256], OUT bf16 [M][768]; tile 128x128 BK=32 */
__global__ __launch_bounds__(256) void gemm_qkv(
    const float* __restrict__ A, const u16* __restrict__ WT,
    const float* __restrict__ bias, u16* __restrict__ OUT) {
  __shared__ __align__(16) u16 lA[128 * 32];
  __shared__ __align__(16) u16 lB[128 * 32];
  /* XCD swizzle: all 6 n-tiles of an m-tile land on one XCD for A L2 reuse */
  int flat = blockIdx.x;          /* 0..9407 */
  int xcd = flat & 7;
  int loc = flat >> 3;            /* 0..1175 */
  int nt = loc % 6;
  int mt = xcd * 196 + loc / 6;
  const int m0 = mt * 128, n0 = nt * 128;
  const int tid = threadIdx.x;
  const int w = tid >> 6, l = tid & 63;
  const int quad = l >> 4, r = l & 15;
  const int wm = (w & 1) * 64, wn = (w >> 1) * 64;

  f32x4 acc[4][4];
#pragma unroll
  for (int i = 0; i < 4; ++i)
#pragma unroll
    for (int j = 0; j < 4; ++j) acc[i][j] = zero4();

  for (int ks = 0; ks < 8; ++ks) {
    const int k0 = ks * 32;
    /* async bf16 weight staging first, then fp32->bf16 A staging overlaps */
#pragma unroll
    for (int cc = 0; cc < 2; ++cc) {
      int c = w * 2 + cc;
      int f = c * 512 + l * 8;
      int row = f >> 5, col = f & 31;
      lds_load16(WT + (size_t)(n0 + row) * 256 + k0 + col, &lB[c * 512]);
    }
    stage_f32_tile(A + (size_t)m0 * 256 + k0, lA, tid);
    __syncthreads();
    bf16x8 af[4], bfr[4];
#pragma unroll
    for (int t = 0; t < 4; ++t) af[t] = *(const bf16x8*)&lA[(wm + 16 * t + r) * 32 + quad * 8];
#pragma unroll
    for (int t = 0; t < 4; ++t) bfr[t] = *(const bf16x8*)&lB[(wn + 16 * t + r) * 32 + quad * 8];
#pragma unroll
    for (int i = 0; i < 4; ++i)
#pragma unroll
      for (int j = 0; j < 4; ++j)
        acc[i][j] = __builtin_amdgcn_mfma_f32_16x16x32_bf16(af[i], bfr[j], acc[i][j], 0, 0, 0);
    __syncthreads();
  }
#pragma unroll
  for (int j = 0; j < 4; ++j) {
    int col = n0 + wn + 16 * j + r;
    float bv = bias[col];
#pragma unroll
    for (int i = 0; i < 4; ++i) {
      int row0 = m0 + wm + 16 * i + quad * 4;
#pragma unroll
      for (int t = 0; t < 4; ++t)
        OUT[(size_t)(row0 + t) * QKV_N + col] = f2bf(acc[i][j][t] + bv);
    }
  }
}

/* ---------------- fused cross attention, one block per window ------------- */
/* qkv bf16 in ws; writes fp32 attention intermediate into d_out             */
__global__ __launch_bounds__(256) void attn_kernel(
    const u16* __restrict__ qkv_x, const u16* __restrict__ qkv_r,
    const float* __restrict__ mask, const float* __restrict__ biasm,
    float* __restrict__ out) {
  __shared__ __align__(16) u16 Pbuf[4][64 * 64];   /* per-wave P (bf16)   */
  __shared__ __align__(16) u16 VTbuf[4][32 * 64];  /* per-wave V^T (bf16) */
  const int b = blockIdx.x;
  const int tid = threadIdx.x;
  const int w = tid >> 6, l = tid & 63;
  const int quad = l >> 4, r = l & 15;
  u16* Pw = Pbuf[w];
  u16* VTw = VTbuf[w];
  const float* mk = mask + (size_t)(b & 63) * (NTOK * NTOK);

  for (int tk = 0; tk < 4; ++tk) {
    const int task = w * 4 + tk;      /* 16 tasks: (out-stream, head) */
    const int sout = task >> 3;       /* 0 = x output, 1 = rgb output */
    const int h = task & 7;
    /* x-output: q from rgb, k/v from x.  rgb-output: q from x, k/v from rgb */
    const u16* qsrc = sout ? qkv_x : qkv_r;
    const u16* kvsrc = sout ? qkv_r : qkv_x;
    float* op = out + (size_t)sout * ((size_t)MTOT * CH);

    /* stage V^T[hd][tok] (zero-padded tok 49..63) */
#pragma unroll 8
    for (int i = 0; i < 32; ++i) {
      u16 v = 0;
      if (l < NTOK) v = kvsrc[(size_t)(b * NTOK + l) * QKV_N + 512 + h * HDIM + i];
      VTw[i * 64 + l] = v;
    }

    /* QK^T: 4x4 tiles of 16x16, K=32=head dim in one MFMA */
    f32x4 acc[4][4];
#pragma unroll
    for (int i = 0; i < 4; ++i)
#pragma unroll
      for (int j = 0; j < 4; ++j) acc[i][j] = zero4();
    bf16x8 qf[4], kf[4];
#pragma unroll
    for (int t = 0; t < 4; ++t) {
      int m = 16 * t + r;
      if (m < NTOK) {
        qf[t] = *(const bf16x8*)&qsrc[(size_t)(b * NTOK + m) * QKV_N + h * HDIM + quad * 8];
        kf[t] = *(const bf16x8*)&kvsrc[(size_t)(b * NTOK + m) * QKV_N + 256 + h * HDIM + quad * 8];
      } else { qf[t] = zero8(); kf[t] = zero8(); }
    }
#pragma unroll
    for (int i = 0; i < 4; ++i)
#pragma unroll
      for (int j = 0; j < 4; ++j)
        acc[i][j] = __builtin_amdgcn_mfma_f32_16x16x32_bf16(qf[i], kf[j], acc[i][j], 0, 0, 0);

    /* scale + bias + mask in C-layout registers; invalid cols -> -1e30 */
    const float* bmh = biasm + h * (NTOK * NTOK);
#pragma unroll
    for (int i = 0; i < 4; ++i)
#pragma unroll
      for (int j = 0; j < 4; ++j)
#pragma unroll
        for (int t = 0; t < 4; ++t) {
          int R = 16 * i + quad * 4 + t, Cc = 16 * j + r;
          float v2;
          if (R < NTOK && Cc < NTOK)
            v2 = acc[i][j][t] * ATT_SCALE + bmh[R * NTOK + Cc] + mk[R * NTOK + Cc];
          else
            v2 = -1e30f;
          acc[i][j][t] = v2;
        }

    /* register softmax: rows fixed per (quad,t,i); cols across j and 16 lanes */
    float mx[4][4], rs[4][4];
#pragma unroll
    for (int i = 0; i < 4; ++i)
#pragma unroll
      for (int t = 0; t < 4; ++t) {
        float m2 = fmaxf(fmaxf(acc[i][0][t], acc[i][1][t]), fmaxf(acc[i][2][t], acc[i][3][t]));
#pragma unroll
        for (int s = 1; s < 16; s <<= 1) m2 = fmaxf(m2, __shfl_xor(m2, s, 64));
        mx[i][t] = m2;
      }
#pragma unroll
    for (int i = 0; i < 4; ++i)
#pragma unroll
      for (int j = 0; j < 4; ++j)
#pragma unroll
        for (int t = 0; t < 4; ++t)
          acc[i][j][t] = __expf(acc[i][j][t] - mx[i][t]);  /* pad cols -> exact 0 */
#pragma unroll
    for (int i = 0; i < 4; ++i)
#pragma unroll
      for (int t = 0; t < 4; ++t) {
        float s2 = acc[i][0][t] + acc[i][1][t] + acc[i][2][t] + acc[i][3][t];
#pragma unroll
        for (int s = 1; s < 16; s <<= 1) s2 += __shfl_xor(s2, s, 64);
        rs[i][t] = s2;
      }

    /* P -> LDS (bf16) to re-enter A-operand layout */
#pragma unroll
    for (int i = 0; i < 4; ++i)
#pragma unroll
      for (int j = 0; j < 4; ++j)
#pragma unroll
        for (int t = 0; t < 4; ++t)
          Pw[(16 * i + quad * 4 + t) * 64 + 16 * j + r] = f2bf(acc[i][j][t]);

    /* PV: rows=q tok (4 tiles), cols=hd (2 tiles), K=64 tok (2 steps) */
    f32x4 acc2[4][2];
#pragma unroll
    for (int i = 0; i < 4; ++i) { acc2[i][0] = zero4(); acc2[i][1] = zero4(); }
#pragma unroll
    for (int ks = 0; ks < 2; ++ks) {
      bf16x8 pf[4], vf[2];
#pragma unroll
      for (int i = 0; i < 4; ++i)
        pf[i] = *(const bf16x8*)&Pw[(16 * i + r) * 64 + ks * 32 + quad * 8];
#pragma unroll
      for (int n2 = 0; n2 < 2; ++n2)
        vf[n2] = *(const bf16x8*)&VTw[(16 * n2 + r) * 64 + ks * 32 + quad * 8];
#pragma unroll
      for (int i = 0; i < 4; ++i)
#pragma unroll
        for (int n2 = 0; n2 < 2; ++n2)
          acc2[i][n2] = __builtin_amdgcn_mfma_f32_16x16x32_bf16(pf[i], vf[n2], acc2[i][n2], 0, 0, 0);
    }

    /* epilogue: normalize by row-sum, store fp32 o[b][tok][h*32+hd] */
#pragma unroll
    for (int i = 0; i < 4; ++i)
#pragma unroll
      for (int t = 0; t < 4; ++t) {
        int R = 16 * i + quad * 4 + t;
        if (R < NTOK) {
          float inv = 1.0f / rs[i][t];
#pragma unroll
          for (int n2 = 0; n2 < 2; ++n2)
            op[(size_t)(b * NTOK + R) * CH + h * HDIM + 16 * n2 + r] = acc2[i][n2][t] * inv;
        }
      }
  }
}

/* ---------------- proj GEMM, in-place on d_out (block owns its 128 rows) - */
/* IO fp32 [M][256] read+write in place; WT bf16 [256][256] */
__global__ __launch_bounds__(256) void gemm_proj(
    const u16* __restrict__ WT_x, const u16* __restrict__ WT_r,
    const float* __restrict__ bias_x, const float* __restrict__ bias_r,
    float* __restrict__ out) {
  __shared__ __align__(16) u16 lA[128 * 32];
  __shared__ __align__(16) u16 lB[256 * 32];
  const int s = blockIdx.y;
  const u16* WT = s ? WT_r : WT_x;
  const float* bias = s ? bias_r : bias_x;
  float* IO = out + (size_t)s * ((size_t)MTOT * CH);
  const int m0 = blockIdx.x * 128;
  const int tid = threadIdx.x;
  const int w = tid >> 6, l = tid & 63;
  const int quad = l >> 4, r = l & 15;
  const int wm = (w & 1) * 64, wn = (w >> 1) * 128;

  f32x4 acc[4][8];
#pragma unroll
  for (int i = 0; i < 4; ++i)
#pragma unroll
    for (int j = 0; j < 8; ++j) acc[i][j] = zero4();

  for (int ks = 0; ks < 8; ++ks) {
    const int k0 = ks * 32;
#pragma unroll
    for (int cc = 0; cc < 4; ++cc) {
      int c = w * 4 + cc;
      int f = c * 512 + l * 8;
      int row = f >> 5, col = f & 31;
      lds_load16(WT + (size_t)row * 256 + k0 + col, &lB[c * 512]);
    }
    stage_f32_tile(IO + (size_t)m0 * 256 + k0, lA, tid);
    __syncthreads();
    bf16x8 af[4], bfr[8];
#pragma unroll
    for (int t = 0; t < 4; ++t) af[t] = *(const bf16x8*)&lA[(wm + 16 * t + r) * 32 + quad * 8];
#pragma unroll
    for (int t = 0; t < 8; ++t) bfr[t] = *(const bf16x8*)&lB[(wn + 16 * t + r) * 32 + quad * 8];
#pragma unroll
    for (int i = 0; i < 4; ++i)
#pragma unroll
      for (int j = 0; j < 8; ++j)
        acc[i][j] = __builtin_amdgcn_mfma_f32_16x16x32_bf16(af[i], bfr[j], acc[i][j], 0, 0, 0);
    __syncthreads();
  }
#pragma unroll
  for (int j = 0; j < 8; ++j) {
    int col = wn + 16 * j + r;
    float bv = bias[col];
#pragma unroll
    for (int i = 0; i < 4; ++i) {
      int row0 = m0 + wm + 16 * i + quad * 4;
#pragma unroll
      for (int t = 0; t < 4; ++t)
        IO[(size_t)(row0 + t) * 256 + col] = acc[i][j][t] + bv;
    }
  }
}

extern "C" void kernel_launch(void* const* d_in, const int* in_sizes, int n_in,
                              void* d_out, int out_size, void* d_ws, size_t ws_size,
                              hipStream_t stream) {
  const float* x        = (const float*)d_in[0];
  const float* rgb      = (const float*)d_in[1];
  const float* mask     = (const float*)d_in[2];
  const float* w_qkv    = (const float*)d_in[3];
  const float* b_qkv    = (const float*)d_in[4];
  const float* w_qkv_r  = (const float*)d_in[5];
  const float* b_qkv_r  = (const float*)d_in[6];
  const float* btab     = (const float*)d_in[7];
  const float* w_proj   = (const float*)d_in[8];
  const float* b_proj   = (const float*)d_in[9];
  const float* w_proj_r = (const float*)d_in[10];
  const float* b_proj_r = (const float*)d_in[11];
  const int* rel_idx    = (const int*)d_in[12];

  char* ws = (char*)d_ws;
  u16* wqT_x  = (u16*)(ws + OFF_WQT_X);
  u16* wqT_r  = (u16*)(ws + OFF_WQT_R);
  u16* wpT_x  = (u16*)(ws + OFF_WPT_X);
  u16* wpT_r  = (u16*)(ws + OFF_WPT_R);
  float* biasm = (float*)(ws + OFF_BIASM);
  u16* qkv_x  = (u16*)(ws + OFF_QKV_X);
  u16* qkv_r  = (u16*)(ws + OFF_QKV_R);
  float* outp = (float*)d_out;

  prep_kernel<<<2124, 256, 0, stream>>>(w_qkv, w_qkv_r, w_proj, w_proj_r,
                                        btab, rel_idx, wqT_x, wqT_r, wpT_x, wpT_r, biasm);
  gemm_qkv<<<9408, 256, 0, stream>>>(x, wqT_x, b_qkv, qkv_x);
  gemm_qkv<<<9408, 256, 0, stream>>>(rgb, wqT_r, b_qkv_r, qkv_r);
  attn_kernel<<<NWIN, 256, 0, stream>>>(qkv_x, qkv_r, mask, biasm, outp);
  gemm_proj<<<dim3(1568, 2), 256, 0, stream>>>(wpT_x, wpT_r, b_proj, b_proj_r, outp);
}